// Round 18
// baseline (2839.621 us; speedup 1.0000x reference)
//
#include <hip/hip_runtime.h>
#include <hip/hip_bf16.h>
#include <cstdint>
#include <cstddef>

// ---------------------------------------------------------------------------
// AudioEncoder (Whisper-style) forward for MI355X.
// B=8, T=4096, n_mels=128, D=1024, H=8 heads (hd=128), F=4096, L=6, S=1024.
// GEMMs: 128x128 tile, 8 waves, BK=64, NBUF=2x16KB (r17 structure).
// MLP2: split-K=2 via gemm_bt2 (BK=32, NBUF=2, 32KB LDS -> 4 blocks/CU =
// 32 waves/CU, double TLP) accumulating with f32 atomicAdd into the carry
// (residual already present; bias folded into the kh=0 half).
// Attention: flash, KVBLK=32 disjoint double buffers (unchanged).
// ---------------------------------------------------------------------------

typedef __bf16 bf16_t;
typedef __bf16 bf16x8 __attribute__((ext_vector_type(8)));
typedef __bf16 bf16x4 __attribute__((ext_vector_type(4)));
typedef float  floatx4 __attribute__((ext_vector_type(4)));

#define NB   8
#define NS   1024
#define ND   1024
#define NT   4096
#define NT1  2048

#define MFMA16(a, b, c) __builtin_amdgcn_mfma_f32_16x16x32_bf16(a, b, c, 0, 0, 0)

#define SBAR() do { __builtin_amdgcn_sched_barrier(0); \
                    __builtin_amdgcn_s_barrier();      \
                    __builtin_amdgcn_sched_barrier(0); } while (0)

__device__ __forceinline__ float gelu_f(float x) {
  const float t = 1.5957691216057308f * (x + 0.044715f * x * x * x);
  return x / (1.0f + __expf(-t));
}

__device__ __forceinline__ void gload16(const void* g, void* l) {
  __builtin_amdgcn_global_load_lds(
      (__attribute__((address_space(1))) void*)(const_cast<void*>(g)),
      (__attribute__((address_space(3))) void*)l, 16, 0, 0);
}

enum { EPI_BF16 = 0, EPI_GELU_BF16 = 2, EPI_GELU_F32 = 3, EPI_RES_F32 = 4, EPI_QKV = 5 };

// 2-D per-XCD chunk remap (chunk = 16(bx) x cby(by), cby = gx*gy/128).
__device__ __forceinline__ void xcd_remap(int& bx, int& by) {
  const int gx = gridDim.x, gy = gridDim.y;
  const int id  = bx + by * gx;
  const int xcd = id & 7;
  const int r   = id >> 3;
  const int cby = (gx * gy) >> 7;
  const int ncx = gx >> 4;
  const int cx  = xcd % ncx, cy = xcd / ncx;
  bx = cx * 16 + (r & 15);
  by = cy * cby + (r >> 4);
}

// ---- r17 BK=64 kernel (unchanged) ----
#define COMPUTE2(BUF, H) { \
    const char* rAd = rA + (BUF) * 16384 + (H) * 8192; \
    const char* rBd = rB + (BUF) * 16384 + (H) * 8192; \
    const bf16x8 a0 = *(const bf16x8*)(rAd +    0); \
    const bf16x8 a1 = *(const bf16x8*)(rAd + 1024); \
    const bf16x8 a2 = *(const bf16x8*)(rAd + 2048); \
    const bf16x8 a3 = *(const bf16x8*)(rAd + 3072); \
    const bf16x8 b0 = *(const bf16x8*)(rBd +    0); \
    const bf16x8 b1 = *(const bf16x8*)(rBd + 1024); \
    acc[0][0] = MFMA16(a0, b0, acc[0][0]); acc[0][1] = MFMA16(a0, b1, acc[0][1]); \
    acc[1][0] = MFMA16(a1, b0, acc[1][0]); acc[1][1] = MFMA16(a1, b1, acc[1][1]); \
    acc[2][0] = MFMA16(a2, b0, acc[2][0]); acc[2][1] = MFMA16(a2, b1, acc[2][1]); \
    acc[3][0] = MFMA16(a3, b0, acc[3][0]); acc[3][1] = MFMA16(a3, b1, acc[3][1]); \
  }

#define KSTEP(BUF, SNEXT_OK) do { \
    if (SNEXT_OK) { \
      gload16(aP,      dA + ((BUF) ^ 1) * 8192);        \
      gload16(aP + 32, dA + ((BUF) ^ 1) * 8192 + 4096); \
    } \
    COMPUTE2(BUF, 0); \
    if (SNEXT_OK) { \
      gload16(bP,      dB + ((BUF) ^ 1) * 8192);        \
      gload16(bP + 32, dB + ((BUF) ^ 1) * 8192 + 4096); \
      aP += 64; bP += 64; \
    } \
    COMPUTE2(BUF, 1); \
    asm volatile("s_waitcnt vmcnt(0)" ::: "memory"); \
    SBAR(); \
  } while (0)

template<int EPI>
__global__ __launch_bounds__(512, 4)
void gemm_bt(const bf16_t* __restrict__ A, long lda,
             const bf16_t* __restrict__ Bm, long ldb,
             void* Cv, long ldc,
             const float* __restrict__ bias, const float* res,
             int K, int swz,
             bf16_t* out2, bf16_t* out3, const float* __restrict__ bias2,
             const float2* __restrict__ rtab)
{
  __shared__ bf16_t sA[2][8192];
  __shared__ bf16_t sB[2][8192];
  const int tid  = threadIdx.x;
  const int wid  = tid >> 6;
  const int lane = tid & 63;
  const int lo = lane & 15, g = lane >> 4;
  const int wr = wid >> 2, wc = wid & 3;

  int bx = blockIdx.x, by = blockIdx.y;
  if (swz) xcd_remap(bx, by);
  const int m0 = bx * 128, n0 = by * 128;
  const int NTK = K >> 6;

  const int lrow = lane >> 2;
  const int lcol = 8 * ((lane & 3) ^ ((lane >> 3) & 3));
  const int rslot = 16 * (g ^ ((lo >> 1) & 3));

  const bf16_t* aP = A  + (long)(m0 + wid * 16 + lrow) * lda + lcol;
  const bf16_t* bP = Bm + (long)(n0 + wid * 16 + lrow) * ldb + lcol;
  bf16_t* const dA = &sA[0][wid * 512];
  bf16_t* const dB = &sB[0][wid * 512];
  const char* const rA = (const char*)&sA[0][0] + (wr * 64 + lo) * 64 + rslot;
  const char* const rB = (const char*)&sB[0][0] + (wc * 32 + lo) * 64 + rslot;

  floatx4 acc[4][2] = {};

  gload16(aP,      dA);         gload16(aP + 32, dA + 4096);
  gload16(bP,      dB);         gload16(bP + 32, dB + 4096);
  aP += 64; bP += 64;
  asm volatile("s_waitcnt vmcnt(0)" ::: "memory");
  SBAR();

#pragma unroll 1
  for (int s = 0; s < NTK; s += 2) {
    KSTEP(0, (s + 1 < NTK));
    KSTEP(1, (s + 2 < NTK));
  }

  if constexpr (EPI == EPI_QKV) {
    const int sect = n0 >> 10;
#pragma unroll
    for (int ni = 0; ni < 2; ++ni) {
      const int col = n0 + wc * 32 + ni * 16 + lo;
      const int c10 = col & 1023;
      float bvs = 0.0f;
      if (sect == 0) bvs = bias[c10];
      else if (sect == 2) bvs = bias2[c10];
#pragma unroll
      for (int mi = 0; mi < 4; ++mi) {
#pragma unroll
        for (int r = 0; r < 4; ++r) {
          const int row = m0 + wr * 64 + mi * 16 + g * 4 + r;
          const int sr = row & 1023;
          float val = acc[mi][ni][r] + bvs;
          if (sect < 2) {
            const float2 t = rtab[(sr << 6) + ((col & 127) >> 1)];
            const float p = __shfl_xor(val, 1);
            val = val * t.x + p * ((col & 1) ? t.y : -t.y);
            bf16_t* dst = sect ? out2 : (bf16_t*)Cv;
            dst[(long)row * 1024 + c10] = (bf16_t)val;
          } else {
            out3[((long)(row >> 10) << 20) + ((long)(col - 2048) << 10) + sr] = (bf16_t)val;
          }
        }
      }
    }
    return;
  }

#pragma unroll
  for (int ni = 0; ni < 2; ++ni) {
    const int col = n0 + wc * 32 + ni * 16 + lo;
    const float bvs = bias ? bias[col] : 0.0f;
#pragma unroll
    for (int mi = 0; mi < 4; ++mi) {
#pragma unroll
      for (int r = 0; r < 4; ++r) {
        const int row = m0 + wr * 64 + mi * 16 + g * 4 + r;
        float v = acc[mi][ni][r] + bvs;
        if constexpr (EPI == EPI_BF16) {
          ((bf16_t*)Cv)[(long)row * ldc + col] = (bf16_t)v;
        } else if constexpr (EPI == EPI_GELU_BF16) {
          ((bf16_t*)Cv)[(long)row * ldc + col] = (bf16_t)gelu_f(v);
        } else if constexpr (EPI == EPI_GELU_F32) {
          ((float*)Cv)[(long)row * ldc + col] = gelu_f(v);
        } else {  // EPI_RES_F32
          const long idx = (long)row * ldc + col;
          ((float*)Cv)[idx] = res[idx] + v;
        }
      }
    }
  }
}

// ---------------------------------------------------------------------------
// gemm_bt2: split-K=2 MLP2 kernel. BK=32, NBUF=2, 32KB LDS -> 4 blocks/CU.
// Grid (64, 16): kh = by>>3 selects K half [kh*HK, +HK); n0 = (by&7)*128.
// Epilogue: atomicAdd into f32 carry (residual already there); kh==0 adds
// bias. Atomics commute -> no ordering hazard between halves.
// ---------------------------------------------------------------------------
#define COMPUTE1(BUF) { \
    const char* rAd = rA + (BUF) * 8192; \
    const char* rBd = rB + (BUF) * 8192; \
    const bf16x8 a0 = *(const bf16x8*)(rAd +    0); \
    const bf16x8 a1 = *(const bf16x8*)(rAd + 1024); \
    const bf16x8 a2 = *(const bf16x8*)(rAd + 2048); \
    const bf16x8 a3 = *(const bf16x8*)(rAd + 3072); \
    const bf16x8 b0 = *(const bf16x8*)(rBd +    0); \
    const bf16x8 b1 = *(const bf16x8*)(rBd + 1024); \
    acc[0][0] = MFMA16(a0, b0, acc[0][0]); acc[0][1] = MFMA16(a0, b1, acc[0][1]); \
    acc[1][0] = MFMA16(a1, b0, acc[1][0]); acc[1][1] = MFMA16(a1, b1, acc[1][1]); \
    acc[2][0] = MFMA16(a2, b0, acc[2][0]); acc[2][1] = MFMA16(a2, b1, acc[2][1]); \
    acc[3][0] = MFMA16(a3, b0, acc[3][0]); acc[3][1] = MFMA16(a3, b1, acc[3][1]); \
  }

#define KSTEP1(BUF, OK) do { \
    if (OK) { \
      gload16(aP, dA + ((BUF) ^ 1) * 4096); \
      gload16(bP, dB + ((BUF) ^ 1) * 4096); \
      aP += 32; bP += 32; \
    } \
    COMPUTE1(BUF); \
    asm volatile("s_waitcnt vmcnt(0)" ::: "memory"); \
    SBAR(); \
  } while (0)

__global__ __launch_bounds__(512, 8)
void gemm_bt2(const bf16_t* __restrict__ A, long lda,
              const bf16_t* __restrict__ Bm, long ldb,
              float* __restrict__ carry, long ldc,
              const float* __restrict__ bias, int HK)
{
  __shared__ bf16_t sA[2][4096];   // 8KB/buf -> 32KB total
  __shared__ bf16_t sB[2][4096];
  const int tid  = threadIdx.x;
  const int wid  = tid >> 6;
  const int lane = tid & 63;
  const int lo = lane & 15, g = lane >> 4;
  const int wr = wid >> 2, wc = wid & 3;

  int bx = blockIdx.x, by = blockIdx.y;
  xcd_remap(bx, by);                 // (64,16): cby=8, ncx=4 -> bijective
  const int kh = by >> 3;
  const int m0 = bx * 128, n0 = (by & 7) * 128;
  const int NTK = HK >> 5;           // 64 steps for HK=2048

  const int lrow = lane >> 2;
  const int lcol = 8 * ((lane & 3) ^ ((lane >> 3) & 3));
  const int rslot = 16 * (g ^ ((lo >> 1) & 3));

  const bf16_t* aP = A  + (long)(m0 + wid * 16 + lrow) * lda + kh * HK + lcol;
  const bf16_t* bP = Bm + (long)(n0 + wid * 16 + lrow) * ldb + kh * HK + lcol;
  bf16_t* const dA = &sA[0][wid * 512];
  bf16_t* const dB = &sB[0][wid * 512];
  const char* const rA = (const char*)&sA[0][0] + (wr * 64 + lo) * 64 + rslot;
  const char* const rB = (const char*)&sB[0][0] + (wc * 32 + lo) * 64 + rslot;

  floatx4 acc[4][2] = {};

  gload16(aP, dA); gload16(bP, dB);
  aP += 32; bP += 32;
  asm volatile("s_waitcnt vmcnt(0)" ::: "memory");
  SBAR();

#pragma unroll 1
  for (int s = 0; s < NTK; s += 2) {   // NTK = 64, even
    KSTEP1(0, (s + 1 < NTK));
    KSTEP1(1, (s + 2 < NTK));
  }

#pragma unroll
  for (int ni = 0; ni < 2; ++ni) {
    const int col = n0 + wc * 32 + ni * 16 + lo;
    const float bvs = (kh == 0) ? bias[col] : 0.0f;
#pragma unroll
    for (int mi = 0; mi < 4; ++mi) {
#pragma unroll
      for (int r = 0; r < 4; ++r) {
        const int row = m0 + wr * 64 + mi * 16 + g * 4 + r;
        atomicAdd(&carry[(long)row * ldc + col], acc[mi][ni][r] + bvs);
      }
    }
  }
}

// ---------------------------------------------------------------------------
// Flash attention (unchanged from round 11).
// ---------------------------------------------------------------------------
__global__ __launch_bounds__(256, 4)
void flash_kernel(const bf16_t* __restrict__ q, const bf16_t* __restrict__ k,
                  const bf16_t* __restrict__ vt, bf16_t* __restrict__ o,
                  const int* __restrict__ xlen)
{
  __shared__ bf16_t sK[2][4096];
  __shared__ bf16_t sV[2][4096];
  __shared__ bf16_t sP[4][512];
  const int tid = threadIdx.x, w = tid >> 6, lane = tid & 63;
  const int lo = lane & 15, g = lane >> 4;
  const int hid = blockIdx.x + (blockIdx.y << 4);
  const int h   = hid & 7;
  const int qx  = (hid >> 3) & 15;
  const int b   = hid >> 7;
  const int q0 = qx * 64 + w * 16;
  const int nv  = xlen[b] >> 2;
  const int nkt = (nv + 31) >> 5;
  const long base = (long)b * 1048576 + (long)h * 128;
  const bf16_t* Qp = q + base;
  const bf16_t* Kp = k + base;
  const bf16_t* Vp = vt + (long)b * 1048576 + ((long)h << 17);

  auto stageKV = [&](int kt, int buf) {
    const int kv0 = kt << 5;
#pragma unroll
    for (int jj = 0; jj < 2; ++jj) {
      const int seg = (w << 1) + jj;
      {
        const int row = (seg << 2) + (lane >> 4);
        const int col = ((lane & 15) << 3) ^ ((row & 7) << 3);
        gload16(Kp + (long)(kv0 + row) * 1024 + col, &sK[buf][seg * 512]);
      }
      {
        const int row = (seg << 4) + (lane >> 2);
        const int col = ((lane & 3) << 3) ^ ((row & 3) << 3);
        gload16(Vp + (long)row * 1024 + kv0 + col, &sV[buf][seg * 512]);
      }
    }
  };

  bf16x8 qf[4];
#pragma unroll
  for (int ks = 0; ks < 4; ++ks)
    qf[ks] = *reinterpret_cast<const bf16x8*>(
        Qp + (long)(q0 + lo) * 1024 + ks * 32 + g * 8);

  floatx4 of[8] = {};
  float m[4], l[4];
#pragma unroll
  for (int r = 0; r < 4; ++r) { m[r] = -1e30f; l[r] = 0.0f; }

  const char* kbase = (const char*)&sK[0][0];
  const char* vbase = (const char*)&sV[0][0];
  char* pbase = (char*)&sP[w][0];
  const int swzK = (lo & 7) << 4;
  const int swzV = (lo & 3) << 4;

  stageKV(0, 0);
  __syncthreads();
  int cur = 0;
#pragma unroll 1
  for (int kt = 0; kt < nkt; ++kt) {
    const int kv0 = kt << 5;
    if (kt + 1 < nkt) stageKV(kt + 1, cur ^ 1);

    floatx4 s[2] = {};
    __builtin_amdgcn_s_setprio(1);
#pragma unroll
    for (int ni = 0; ni < 2; ++ni) {
#pragma unroll
      for (int ks = 0; ks < 4; ++ks) {
        const bf16x8 bv = *reinterpret_cast<const bf16x8*>(
            kbase + cur * 8192 + (ni * 16 + lo) * 256 + ((ks * 64 + (g << 4)) ^ swzK));
        s[ni] = MFMA16(qf[ks], bv, s[ni]);
      }
    }
    __builtin_amdgcn_s_setprio(0);

    float pmv[4];
#pragma unroll
    for (int r = 0; r < 4; ++r) {
      float pm = -1e30f;
#pragma unroll
      for (int ni = 0; ni < 2; ++ni) {
        float val = s[ni][r];
        if (kv0 + ni * 16 + lo >= nv) val = -1e30f;
        pm = fmaxf(pm, val);
      }
      pm = fmaxf(pm, __shfl_xor(pm, 1)); pm = fmaxf(pm, __shfl_xor(pm, 2));
      pm = fmaxf(pm, __shfl_xor(pm, 4)); pm = fmaxf(pm, __shfl_xor(pm, 8));
      pmv[r] = pm;
    }
    const bool skip = __all((pmv[0] <= m[0] + 8.0f) & (pmv[1] <= m[1] + 8.0f) &
                            (pmv[2] <= m[2] + 8.0f) & (pmv[3] <= m[3] + 8.0f));

#pragma unroll
    for (int r = 0; r < 4; ++r) {
      float mn = m[r];
      if (!skip) {
        mn = fmaxf(m[r], pmv[r]);
        const float sc = __expf(m[r] - mn);
        l[r] *= sc;
#pragma unroll
        for (int nd = 0; nd < 8; ++nd) of[nd][r] *= sc;
        m[r] = mn;
      }
      const int qrow = g * 4 + r;
      const int sw = (qrow & 3) << 4;
      float ss = 0.0f;
#pragma unroll
      for (int ni = 0; ni < 2; ++ni) {
        float val = s[ni][r];
        if (kv0 + ni * 16 + lo >= nv) val = -1e30f;
        const float p = __expf(val - mn);
        ss += p;
        *(bf16_t*)(pbase + qrow * 64 + (((ni << 5) + (lo << 1)) ^ sw)) = (bf16_t)p;
      }
      ss += __shfl_xor(ss, 1); ss += __shfl_xor(ss, 2);
      ss += __shfl_xor(ss, 4); ss += __shfl_xor(ss, 8);
      l[r] += ss;
    }

    asm volatile("s_waitcnt lgkmcnt(0)" ::: "memory");
    __builtin_amdgcn_sched_barrier(0);

    __builtin_amdgcn_s_setprio(1);
    {
      const bf16x8 av = *reinterpret_cast<const bf16x8*>(
          pbase + lo * 64 + ((g << 4) ^ swzV));
#pragma unroll
      for (int nd = 0; nd < 8; ++nd) {
        const bf16x8 bv = *reinterpret_cast<const bf16x8*>(
            vbase + cur * 8192 + (nd * 16 + lo) * 64 + ((g << 4) ^ swzV));
        of[nd] = MFMA16(av, bv, of[nd]);
      }
    }
    __builtin_amdgcn_s_setprio(0);
    __syncthreads();
    cur ^= 1;
  }

#pragma unroll
  for (int r = 0; r < 4; ++r) {
    const float inv = 1.0f / l[r];
    const long rb = base + (long)(q0 + g * 4 + r) * 1024;
#pragma unroll
    for (int nd = 0; nd < 8; ++nd)
      o[rb + nd * 16 + lo] = (bf16_t)(of[nd][r] * inv);
  }
}

// LayerNorm: one block per row of 1024 f32 -> bf16
__global__ __launch_bounds__(256)
void ln_kernel(const float* __restrict__ x, bf16_t* __restrict__ y,
               const float* __restrict__ w, const float* __restrict__ b)
{
  const long row = blockIdx.x;
  const float4 v = reinterpret_cast<const float4*>(x + row * ND)[threadIdx.x];
  float s  = v.x + v.y + v.z + v.w;
  float ss = v.x * v.x + v.y * v.y + v.z * v.z + v.w * v.w;
#pragma unroll
  for (int off = 32; off; off >>= 1) { s += __shfl_down(s, off); ss += __shfl_down(ss, off); }
  __shared__ float sh[8];
  if ((threadIdx.x & 63) == 0) { sh[threadIdx.x >> 6] = s; sh[4 + (threadIdx.x >> 6)] = ss; }
  __syncthreads();
  const float tot  = sh[0] + sh[1] + sh[2] + sh[3];
  const float tot2 = sh[4] + sh[5] + sh[6] + sh[7];
  const float mean = tot * (1.0f / ND);
  const float var  = tot2 * (1.0f / ND) - mean * mean;
  const float rstd = rsqrtf(var + 1e-5f);
  const int i0 = threadIdx.x * 4;
  const float vv[4] = {v.x, v.y, v.z, v.w};
  bf16x4 o;
#pragma unroll
  for (int j = 0; j < 4; ++j)
    o[j] = (bf16_t)((vv[j] - mean) * rstd * w[i0 + j] + b[i0 + j]);
  reinterpret_cast<bf16x4*>(y + row * ND)[threadIdx.x] = o;
}

// pre-scaled rope table
__global__ __launch_bounds__(256)
void rtab_kernel(float2* __restrict__ tab)
{
  const int idx = blockIdx.x * 256 + threadIdx.x;
  const int s = idx >> 6, i = idx & 63;
  const float freq = __expf((float)i * -0.14391156831212787f);
  float sn, cs;
  sincosf((float)s * freq, &sn, &cs);
  const float sc = 0.29730177875068026f;
  tab[idx] = make_float2(cs * sc, sn * sc);
}

// im2col conv1
__global__ __launch_bounds__(256)
void im2col1_kernel(const float* __restrict__ x, bf16_t* __restrict__ a)
{
  const long idx = (long)blockIdx.x * 256 + threadIdx.x;
  if (idx >= (long)NB * NT1 * 384) return;
  const int  k = (int)(idx % 384);
  const long m = idx / 384;
  const int i = k / 3, kk = k - 3 * i;
  const int t = (int)(m & (NT1 - 1));
  const int b = (int)(m >> 11);
  const int tt = 2 * t + kk - 1;
  float v = 0.0f;
  if (tt >= 0 && tt < NT) v = x[((long)b * 128 + i) * NT + tt];
  a[idx] = (bf16_t)v;
}

// im2col conv2
__global__ __launch_bounds__(256)
void im2col2_kernel(const bf16_t* __restrict__ h1, bf16_t* __restrict__ a)
{
  const long idx = (long)blockIdx.x * 256 + threadIdx.x;
  if (idx >= (long)NB * NS * 3072) return;
  const int  k = (int)(idx % 3072);
  const long m = idx / 3072;
  const int i = k / 3, kk = k - 3 * i;
  const int t = (int)(m & (NS - 1));
  const int b = (int)(m >> 10);
  const int tt = 2 * t + kk - 1;
  bf16_t v = (bf16_t)0.0f;
  if (tt >= 0 && tt < NT1) v = h1[((long)b * NT1 + tt) * ND + i];
  a[idx] = v;
}

__global__ void ylen_kernel(const int* __restrict__ xlen, float* __restrict__ ylen)
{
  const int b = threadIdx.x;
  if (b < NB) {
    const int y1 = (xlen[b] + 1) >> 1;
    ylen[b] = (float)((y1 + 1) >> 1);
  }
}

__global__ __launch_bounds__(256)
void cvt_kernel(const float* __restrict__ in, bf16_t* __restrict__ out, long n)
{
  const long i = ((long)blockIdx.x * 256 + threadIdx.x) * 4;
  if (i >= n) return;
  const float4 v = *reinterpret_cast<const float4*>(in + i);
  bf16x4 o;
  o[0] = (bf16_t)v.x; o[1] = (bf16_t)v.y; o[2] = (bf16_t)v.z; o[3] = (bf16_t)v.w;
  *reinterpret_cast<bf16x4*>(out + i) = o;
}

// per-layer weight conversion in ONE launch
__global__ __launch_bounds__(256)
void cvt_layer_kernel(const float* __restrict__ qw, const float* __restrict__ kw,
                      const float* __restrict__ vw, const float* __restrict__ ow,
                      const float* __restrict__ w1, const float* __restrict__ w2,
                      bf16_t* __restrict__ wqkv, bf16_t* __restrict__ wo,
                      bf16_t* __restrict__ w1b, bf16_t* __restrict__ w2b)
{
  const long i = ((long)blockIdx.x * 256 + threadIdx.x) * 4;
  const float* src; bf16_t* dst;
  if (i < 3145728) {
    dst = wqkv + i;
    if (i < 1048576)      { src = qw + i; }
    else if (i < 2097152) { src = kw + (i - 1048576); }
    else                  { src = vw + (i - 2097152); }
  } else if (i < 4194304) { src = ow + (i - 3145728); dst = wo  + (i - 3145728); }
  else if (i < 8388608)   { src = w1 + (i - 4194304); dst = w1b + (i - 4194304); }
  else                    { src = w2 + (i - 8388608); dst = w2b + (i - 8388608); }
  const float4 v = *reinterpret_cast<const float4*>(src);
  bf16x4 o;
  o[0] = (bf16_t)v.x; o[1] = (bf16_t)v.y; o[2] = (bf16_t)v.z; o[3] = (bf16_t)v.w;
  *reinterpret_cast<bf16x4*>(dst) = o;
}

extern "C" void kernel_launch(void* const* d_in, const int* in_sizes, int n_in,
                              void* d_out, int out_size, void* d_ws, size_t ws_size,
                              hipStream_t stream)
{
  const float* x         = (const float*)d_in[0];
  const int*   x_len     = (const int*)  d_in[1];
  const float* conv1_w   = (const float*)d_in[2];
  const float* conv1_b   = (const float*)d_in[3];
  const float* conv2_w   = (const float*)d_in[4];
  const float* conv2_b   = (const float*)d_in[5];
  const float* attn_ln_w = (const float*)d_in[6];
  const float* attn_ln_b = (const float*)d_in[7];
  const float* q_w   = (const float*)d_in[8];
  const float* q_b   = (const float*)d_in[9];
  const float* k_w   = (const float*)d_in[10];
  const float* v_w   = (const float*)d_in[11];
  const float* v_b   = (const float*)d_in[12];
  const float* out_w = (const float*)d_in[13];
  const float* out_b = (const float*)d_in[14];
  const float* mlp_ln_w = (const float*)d_in[15];
  const float* mlp_ln_b = (const float*)d_in[16];
  const float* mlp1_w = (const float*)d_in[17];
  const float* mlp1_b = (const float*)d_in[18];
  const float* mlp2_w = (const float*)d_in[19];
  const float* mlp2_b = (const float*)d_in[20];
  float* outp = (float*)d_out;
  (void)in_sizes; (void)n_in; (void)out_size;

  const long MB = 1024L * 1024;
  char* ws = (char*)d_ws;
  size_t off = 0;
  auto alloc = [&](size_t bytes) -> char* {
    char* p = ws + off;
    off += (bytes + 255) & ~(size_t)255;
    return p;
  };
  bf16_t* ybuf  = (bf16_t*)alloc(16 * MB);
  bf16_t* qbuf  = (bf16_t*)alloc(16 * MB);
  char*   R     = alloc(64 * MB);
  char*   wA    = alloc(25 * MB);
  const size_t required = off;

  bf16_t* a1  = ybuf;
  bf16_t* h1  = qbuf;
  bf16_t* a2  = (bf16_t*)(R + 16 * MB);
  bf16_t* c2w = (bf16_t*)wA;
  bf16_t* c1w = (bf16_t*)(wA + 8 * MB);
  float2* rtab = (float2*)(wA + 6 * MB);
  bf16_t* wqkv = (bf16_t*)wA;
  bf16_t* wo   = (bf16_t*)(wA + 6 * MB + 512 * 1024);
  bf16_t* w1b  = (bf16_t*)(wA + 9 * MB);
  bf16_t* w2b  = (bf16_t*)(wA + 17 * MB);
  bf16_t* kbuf = (bf16_t*)R;
  bf16_t* vt   = (bf16_t*)(R + 16 * MB);
  bf16_t* hid  = (bf16_t*)R;

  if (required > ws_size) {
    ylen_kernel<<<dim3(1), 64, 0, stream>>>(x_len, outp + 8L * 1024 * 1024);
    return;
  }

  auto cvt = [&](const float* in, bf16_t* o, long n) {
    cvt_kernel<<<dim3((unsigned)(n / 1024)), 256, 0, stream>>>(in, o, n);
  };

  rtab_kernel<<<dim3(256), 256, 0, stream>>>(rtab);

  // ---- conv stem ----
  cvt(conv1_w, c1w, 1024L * 384);
  cvt(conv2_w, c2w, 1024L * 3072);
  im2col1_kernel<<<dim3((unsigned)((16384L * 384) / 256)), 256, 0, stream>>>(x, a1);
  gemm_bt<EPI_GELU_BF16><<<dim3(128, 8), 512, 0, stream>>>(
      a1, 384, c1w, 384, h1, 1024, conv1_b, nullptr, 384, 1,
      nullptr, nullptr, nullptr, nullptr);
  im2col2_kernel<<<dim3((unsigned)((8192L * 3072) / 256)), 256, 0, stream>>>(h1, a2);
  gemm_bt<EPI_GELU_F32><<<dim3(64, 8), 512, 0, stream>>>(
      a2, 3072, c2w, 3072, outp /*carry*/, 1024, conv2_b, nullptr, 3072, 1,
      nullptr, nullptr, nullptr, nullptr);

  float* carry = outp;  // f32 residual stream lives in d_out

  for (int l = 0; l < 6; ++l) {
    cvt_layer_kernel<<<dim3(12288), 256, 0, stream>>>(
        q_w + (long)l * 1048576, k_w + (long)l * 1048576, v_w + (long)l * 1048576,
        out_w + (long)l * 1048576, mlp1_w + (long)l * 4194304, mlp2_w + (long)l * 4194304,
        wqkv, wo, w1b, w2b);

    ln_kernel<<<dim3(8192), 256, 0, stream>>>(carry, ybuf, attn_ln_w + l * 1024, attn_ln_b + l * 1024);

    // fused QKV projection + rope/scale + V-transpose (N=3072)
    gemm_bt<EPI_QKV><<<dim3(64, 24), 512, 0, stream>>>(
        ybuf, 1024, wqkv, 1024, qbuf, 1024,
        q_b + l * 1024, nullptr, 1024, 1, kbuf, vt, v_b + l * 1024, rtab);

    // flash attention: O overwrites Q in place
    flash_kernel<<<dim3(16, 64), 256, 0, stream>>>(qbuf, kbuf, vt, qbuf, x_len);

    // carry += O @ ow^T + ob
    gemm_bt<EPI_RES_F32><<<dim3(64, 8), 512, 0, stream>>>(
        qbuf, 1024, wo, 1024, carry, 1024,
        out_b + l * 1024, carry, 1024, 1, nullptr, nullptr, nullptr, nullptr);

    ln_kernel<<<dim3(8192), 256, 0, stream>>>(carry, ybuf, mlp_ln_w + l * 1024, mlp_ln_b + l * 1024);

    gemm_bt<EPI_GELU_BF16><<<dim3(64, 32), 512, 0, stream>>>(
        ybuf, 1024, w1b, 1024, hid, 4096,
        mlp1_b + (long)l * 4096, nullptr, 1024, 1, nullptr, nullptr, nullptr, nullptr);

    // carry += hid @ w2^T + b2   -- split-K=2, atomic accumulate
    gemm_bt2<<<dim3(64, 16), 512, 0, stream>>>(
        hid, 4096, w2b, 4096, carry, 1024, mlp2_b + l * 1024, 2048);
  }

  ylen_kernel<<<dim3(1), 64, 0, stream>>>(x_len, outp + 8L * 1024 * 1024);
}

// Round 19
// 2600.000 us; speedup vs baseline: 1.0922x; 1.0922x over previous
//
#include <hip/hip_runtime.h>
#include <hip/hip_bf16.h>
#include <cstdint>
#include <cstddef>

// ---------------------------------------------------------------------------
// AudioEncoder (Whisper-style) forward for MI355X.  (r17 configuration —
// best measured: 2604 us. r18's split-K+atomicAdd experiment reverted:
// TLP rose (occ 39->69%) but device-scope atomics cost more than the gain.)
// GEMMs: 128x128 tile, 8 waves, BK=64, NBUF=2x16KB, one vmcnt(0)+barrier
// per 64-K step, hoisted pointers + literal LDS offsets, read-side XOR
// swizzle, 2-D per-XCD chunking.
// Attention: flash, KVBLK=32 disjoint double buffers.
// ---------------------------------------------------------------------------

typedef __bf16 bf16_t;
typedef __bf16 bf16x8 __attribute__((ext_vector_type(8)));
typedef __bf16 bf16x4 __attribute__((ext_vector_type(4)));
typedef float  floatx4 __attribute__((ext_vector_type(4)));

#define NB   8
#define NS   1024
#define ND   1024
#define NT   4096
#define NT1  2048

#define MFMA16(a, b, c) __builtin_amdgcn_mfma_f32_16x16x32_bf16(a, b, c, 0, 0, 0)

#define SBAR() do { __builtin_amdgcn_sched_barrier(0); \
                    __builtin_amdgcn_s_barrier();      \
                    __builtin_amdgcn_sched_barrier(0); } while (0)

__device__ __forceinline__ float gelu_f(float x) {
  const float t = 1.5957691216057308f * (x + 0.044715f * x * x * x);
  return x / (1.0f + __expf(-t));
}

__device__ __forceinline__ void gload16(const void* g, void* l) {
  __builtin_amdgcn_global_load_lds(
      (__attribute__((address_space(1))) void*)(const_cast<void*>(g)),
      (__attribute__((address_space(3))) void*)l, 16, 0, 0);
}

enum { EPI_BF16 = 0, EPI_GELU_BF16 = 2, EPI_GELU_F32 = 3, EPI_RES_F32 = 4, EPI_QKV = 5 };

// 2-D per-XCD chunk remap (chunk = 16(bx) x cby(by), cby = gx*gy/128).
__device__ __forceinline__ void xcd_remap(int& bx, int& by) {
  const int gx = gridDim.x, gy = gridDim.y;
  const int id  = bx + by * gx;
  const int xcd = id & 7;
  const int r   = id >> 3;
  const int cby = (gx * gy) >> 7;
  const int ncx = gx >> 4;
  const int cx  = xcd % ncx, cy = xcd / ncx;
  bx = cx * 16 + (r & 15);
  by = cy * cby + (r >> 4);
}

// compute K-half H of buffer BUF (both literals): 6 LDS frag reads, 8 MFMA.
// Byte units: buffer stride 16384B (8192 elems), half stride 8192B, row 64B.
#define COMPUTE2(BUF, H) { \
    const char* rAd = rA + (BUF) * 16384 + (H) * 8192; \
    const char* rBd = rB + (BUF) * 16384 + (H) * 8192; \
    const bf16x8 a0 = *(const bf16x8*)(rAd +    0); \
    const bf16x8 a1 = *(const bf16x8*)(rAd + 1024); \
    const bf16x8 a2 = *(const bf16x8*)(rAd + 2048); \
    const bf16x8 a3 = *(const bf16x8*)(rAd + 3072); \
    const bf16x8 b0 = *(const bf16x8*)(rBd +    0); \
    const bf16x8 b1 = *(const bf16x8*)(rBd + 1024); \
    acc[0][0] = MFMA16(a0, b0, acc[0][0]); acc[0][1] = MFMA16(a0, b1, acc[0][1]); \
    acc[1][0] = MFMA16(a1, b0, acc[1][0]); acc[1][1] = MFMA16(a1, b1, acc[1][1]); \
    acc[2][0] = MFMA16(a2, b0, acc[2][0]); acc[2][1] = MFMA16(a2, b1, acc[2][1]); \
    acc[3][0] = MFMA16(a3, b0, acc[3][0]); acc[3][1] = MFMA16(a3, b1, acc[3][1]); \
  }

// one BK=64 step on buffer BUF; stages tile s+1 into BUF^1 (guarded).
// Element units for LDS dests: buf*8192 + half*4096.
#define KSTEP(BUF, SNEXT_OK) do { \
    if (SNEXT_OK) { \
      gload16(aP,      dA + ((BUF) ^ 1) * 8192);        \
      gload16(aP + 32, dA + ((BUF) ^ 1) * 8192 + 4096); \
    } \
    COMPUTE2(BUF, 0); \
    if (SNEXT_OK) { \
      gload16(bP,      dB + ((BUF) ^ 1) * 8192);        \
      gload16(bP + 32, dB + ((BUF) ^ 1) * 8192 + 4096); \
      aP += 64; bP += 64; \
    } \
    COMPUTE2(BUF, 1); \
    asm volatile("s_waitcnt vmcnt(0)" ::: "memory"); \
    SBAR(); \
  } while (0)

template<int EPI>
__global__ __launch_bounds__(512, 4)
void gemm_bt(const bf16_t* __restrict__ A, long lda,
             const bf16_t* __restrict__ Bm, long ldb,
             void* Cv, long ldc,
             const float* __restrict__ bias, const float* res,
             int K, int swz,
             bf16_t* out2, bf16_t* out3, const float* __restrict__ bias2,
             const float2* __restrict__ rtab)
{
  __shared__ bf16_t sA[2][8192];   // [buf][half 4096 elems][8 segs x 512]
  __shared__ bf16_t sB[2][8192];   // 16KB per buffer; 64KB LDS total
  const int tid  = threadIdx.x;
  const int wid  = tid >> 6;
  const int lane = tid & 63;
  const int lo = lane & 15, g = lane >> 4;
  const int wr = wid >> 2, wc = wid & 3;

  int bx = blockIdx.x, by = blockIdx.y;
  if (swz) xcd_remap(bx, by);
  const int m0 = bx * 128, n0 = by * 128;
  const int NTK = K >> 6;            // BK=64 steps; all K give even NTK

  const int lrow = lane >> 2;
  const int lcol = 8 * ((lane & 3) ^ ((lane >> 3) & 3));   // inv-swizzled src
  const int rslot = 16 * (g ^ ((lo >> 1) & 3));            // read-side XOR

  const bf16_t* aP = A  + (long)(m0 + wid * 16 + lrow) * lda + lcol;
  const bf16_t* bP = Bm + (long)(n0 + wid * 16 + lrow) * ldb + lcol;
  bf16_t* const dA = &sA[0][wid * 512];
  bf16_t* const dB = &sB[0][wid * 512];
  const char* const rA = (const char*)&sA[0][0] + (wr * 64 + lo) * 64 + rslot;
  const char* const rB = (const char*)&sB[0][0] + (wc * 32 + lo) * 64 + rslot;

  floatx4 acc[4][2] = {};

  // prologue: stage tile 0 (both halves of A and B), drain, barrier
  gload16(aP,      dA);         gload16(aP + 32, dA + 4096);
  gload16(bP,      dB);         gload16(bP + 32, dB + 4096);
  aP += 64; bP += 64;
  asm volatile("s_waitcnt vmcnt(0)" ::: "memory");
  SBAR();

#pragma unroll 1
  for (int s = 0; s < NTK; s += 2) {       // NTK even for all K in use
    KSTEP(0, (s + 1 < NTK));
    KSTEP(1, (s + 2 < NTK));
  }

  // ---- epilogue (wave covers rows wr*64+[0,64), cols wc*32+[0,32)) ----
  if constexpr (EPI == EPI_QKV) {
    const int sect = n0 >> 10;        // 0=Q 1=K 2=V
#pragma unroll
    for (int ni = 0; ni < 2; ++ni) {
      const int col = n0 + wc * 32 + ni * 16 + lo;
      const int c10 = col & 1023;
      float bvs = 0.0f;
      if (sect == 0) bvs = bias[c10];
      else if (sect == 2) bvs = bias2[c10];
#pragma unroll
      for (int mi = 0; mi < 4; ++mi) {
#pragma unroll
        for (int r = 0; r < 4; ++r) {
          const int row = m0 + wr * 64 + mi * 16 + g * 4 + r;
          const int sr = row & 1023;
          float val = acc[mi][ni][r] + bvs;
          if (sect < 2) {             // rope + scale (table pre-scaled)
            const float2 t = rtab[(sr << 6) + ((col & 127) >> 1)];
            const float p = __shfl_xor(val, 1);
            val = val * t.x + p * ((col & 1) ? t.y : -t.y);
            bf16_t* dst = sect ? out2 : (bf16_t*)Cv;
            dst[(long)row * 1024 + c10] = (bf16_t)val;
          } else {                    // vt[b][h*128+d][s]
            out3[((long)(row >> 10) << 20) + ((long)(col - 2048) << 10) + sr] = (bf16_t)val;
          }
        }
      }
    }
    return;
  }

#pragma unroll
  for (int ni = 0; ni < 2; ++ni) {
    const int col = n0 + wc * 32 + ni * 16 + lo;
    const float bvs = bias ? bias[col] : 0.0f;
#pragma unroll
    for (int mi = 0; mi < 4; ++mi) {
#pragma unroll
      for (int r = 0; r < 4; ++r) {
        const int row = m0 + wr * 64 + mi * 16 + g * 4 + r;
        float v = acc[mi][ni][r] + bvs;
        if constexpr (EPI == EPI_BF16) {
          ((bf16_t*)Cv)[(long)row * ldc + col] = (bf16_t)v;
        } else if constexpr (EPI == EPI_GELU_BF16) {
          ((bf16_t*)Cv)[(long)row * ldc + col] = (bf16_t)gelu_f(v);
        } else if constexpr (EPI == EPI_GELU_F32) {
          ((float*)Cv)[(long)row * ldc + col] = gelu_f(v);
        } else {  // EPI_RES_F32
          const long idx = (long)row * ldc + col;
          ((float*)Cv)[idx] = res[idx] + v;
        }
      }
    }
  }
}

// ---------------------------------------------------------------------------
// Flash attention (unchanged from round 11): grid (16, 64), 4 waves/block,
// wave owns 16 q-rows. KVBLK=32 true disjoint double buffers; LDS 36KB.
// ---------------------------------------------------------------------------
__global__ __launch_bounds__(256, 4)
void flash_kernel(const bf16_t* __restrict__ q, const bf16_t* __restrict__ k,
                  const bf16_t* __restrict__ vt, bf16_t* __restrict__ o,
                  const int* __restrict__ xlen)
{
  __shared__ bf16_t sK[2][4096];   // [buf][kv=32][d=128]
  __shared__ bf16_t sV[2][4096];   // [buf][d=128][kv=32]
  __shared__ bf16_t sP[4][512];    // per-wave [q=16][kv=32]
  const int tid = threadIdx.x, w = tid >> 6, lane = tid & 63;
  const int lo = lane & 15, g = lane >> 4;
  const int hid = blockIdx.x + (blockIdx.y << 4);
  const int h   = hid & 7;
  const int qx  = (hid >> 3) & 15;
  const int b   = hid >> 7;
  const int q0 = qx * 64 + w * 16;
  const int nv  = xlen[b] >> 2;
  const int nkt = (nv + 31) >> 5;
  const long base = (long)b * 1048576 + (long)h * 128;
  const bf16_t* Qp = q + base;
  const bf16_t* Kp = k + base;
  const bf16_t* Vp = vt + (long)b * 1048576 + ((long)h << 17);

  auto stageKV = [&](int kt, int buf) {
    const int kv0 = kt << 5;
#pragma unroll
    for (int jj = 0; jj < 2; ++jj) {
      const int seg = (w << 1) + jj;
      {
        const int row = (seg << 2) + (lane >> 4);
        const int col = ((lane & 15) << 3) ^ ((row & 7) << 3);
        gload16(Kp + (long)(kv0 + row) * 1024 + col, &sK[buf][seg * 512]);
      }
      {
        const int row = (seg << 4) + (lane >> 2);
        const int col = ((lane & 3) << 3) ^ ((row & 3) << 3);
        gload16(Vp + (long)row * 1024 + kv0 + col, &sV[buf][seg * 512]);
      }
    }
  };

  bf16x8 qf[4];
#pragma unroll
  for (int ks = 0; ks < 4; ++ks)
    qf[ks] = *reinterpret_cast<const bf16x8*>(
        Qp + (long)(q0 + lo) * 1024 + ks * 32 + g * 8);

  floatx4 of[8] = {};
  float m[4], l[4];
#pragma unroll
  for (int r = 0; r < 4; ++r) { m[r] = -1e30f; l[r] = 0.0f; }

  const char* kbase = (const char*)&sK[0][0];
  const char* vbase = (const char*)&sV[0][0];
  char* pbase = (char*)&sP[w][0];
  const int swzK = (lo & 7) << 4;
  const int swzV = (lo & 3) << 4;

  stageKV(0, 0);
  __syncthreads();
  int cur = 0;
#pragma unroll 1
  for (int kt = 0; kt < nkt; ++kt) {
    const int kv0 = kt << 5;
    if (kt + 1 < nkt) stageKV(kt + 1, cur ^ 1);

    floatx4 s[2] = {};
    __builtin_amdgcn_s_setprio(1);
#pragma unroll
    for (int ni = 0; ni < 2; ++ni) {
#pragma unroll
      for (int ks = 0; ks < 4; ++ks) {
        const bf16x8 bv = *reinterpret_cast<const bf16x8*>(
            kbase + cur * 8192 + (ni * 16 + lo) * 256 + ((ks * 64 + (g << 4)) ^ swzK));
        s[ni] = MFMA16(qf[ks], bv, s[ni]);
      }
    }
    __builtin_amdgcn_s_setprio(0);

    float pmv[4];
#pragma unroll
    for (int r = 0; r < 4; ++r) {
      float pm = -1e30f;
#pragma unroll
      for (int ni = 0; ni < 2; ++ni) {
        float val = s[ni][r];
        if (kv0 + ni * 16 + lo >= nv) val = -1e30f;
        pm = fmaxf(pm, val);
      }
      pm = fmaxf(pm, __shfl_xor(pm, 1)); pm = fmaxf(pm, __shfl_xor(pm, 2));
      pm = fmaxf(pm, __shfl_xor(pm, 4)); pm = fmaxf(pm, __shfl_xor(pm, 8));
      pmv[r] = pm;
    }
    const bool skip = __all((pmv[0] <= m[0] + 8.0f) & (pmv[1] <= m[1] + 8.0f) &
                            (pmv[2] <= m[2] + 8.0f) & (pmv[3] <= m[3] + 8.0f));

#pragma unroll
    for (int r = 0; r < 4; ++r) {
      float mn = m[r];
      if (!skip) {
        mn = fmaxf(m[r], pmv[r]);
        const float sc = __expf(m[r] - mn);
        l[r] *= sc;
#pragma unroll
        for (int nd = 0; nd < 8; ++nd) of[nd][r] *= sc;
        m[r] = mn;
      }
      const int qrow = g * 4 + r;
      const int sw = (qrow & 3) << 4;
      float ss = 0.0f;
#pragma unroll
      for (int ni = 0; ni < 2; ++ni) {
        float val = s[ni][r];
        if (kv0 + ni * 16 + lo >= nv) val = -1e30f;
        const float p = __expf(val - mn);
        ss += p;
        *(bf16_t*)(pbase + qrow * 64 + (((ni << 5) + (lo << 1)) ^ sw)) = (bf16_t)p;
      }
      ss += __shfl_xor(ss, 1); ss += __shfl_xor(ss, 2);
      ss += __shfl_xor(ss, 4); ss += __shfl_xor(ss, 8);
      l[r] += ss;
    }

    asm volatile("s_waitcnt lgkmcnt(0)" ::: "memory");
    __builtin_amdgcn_sched_barrier(0);

    __builtin_amdgcn_s_setprio(1);
    {
      const bf16x8 av = *reinterpret_cast<const bf16x8*>(
          pbase + lo * 64 + ((g << 4) ^ swzV));
#pragma unroll
      for (int nd = 0; nd < 8; ++nd) {
        const bf16x8 bv = *reinterpret_cast<const bf16x8*>(
            vbase + cur * 8192 + (nd * 16 + lo) * 64 + ((g << 4) ^ swzV));
        of[nd] = MFMA16(av, bv, of[nd]);
      }
    }
    __builtin_amdgcn_s_setprio(0);
    __syncthreads();
    cur ^= 1;
  }

#pragma unroll
  for (int r = 0; r < 4; ++r) {
    const float inv = 1.0f / l[r];
    const long rb = base + (long)(q0 + g * 4 + r) * 1024;
#pragma unroll
    for (int nd = 0; nd < 8; ++nd)
      o[rb + nd * 16 + lo] = (bf16_t)(of[nd][r] * inv);
  }
}

// LayerNorm: one block per row of 1024 f32 -> bf16
__global__ __launch_bounds__(256)
void ln_kernel(const float* __restrict__ x, bf16_t* __restrict__ y,
               const float* __restrict__ w, const float* __restrict__ b)
{
  const long row = blockIdx.x;
  const float4 v = reinterpret_cast<const float4*>(x + row * ND)[threadIdx.x];
  float s  = v.x + v.y + v.z + v.w;
  float ss = v.x * v.x + v.y * v.y + v.z * v.z + v.w * v.w;
#pragma unroll
  for (int off = 32; off; off >>= 1) { s += __shfl_down(s, off); ss += __shfl_down(ss, off); }
  __shared__ float sh[8];
  if ((threadIdx.x & 63) == 0) { sh[threadIdx.x >> 6] = s; sh[4 + (threadIdx.x >> 6)] = ss; }
  __syncthreads();
  const float tot  = sh[0] + sh[1] + sh[2] + sh[3];
  const float tot2 = sh[4] + sh[5] + sh[6] + sh[7];
  const float mean = tot * (1.0f / ND);
  const float var  = tot2 * (1.0f / ND) - mean * mean;
  const float rstd = rsqrtf(var + 1e-5f);
  const int i0 = threadIdx.x * 4;
  const float vv[4] = {v.x, v.y, v.z, v.w};
  bf16x4 o;
#pragma unroll
  for (int j = 0; j < 4; ++j)
    o[j] = (bf16_t)((vv[j] - mean) * rstd * w[i0 + j] + b[i0 + j]);
  reinterpret_cast<bf16x4*>(y + row * ND)[threadIdx.x] = o;
}

// pre-scaled rope table: rtab[s*64+i] = (cos, sin)(s*f_i) * 128^-0.25
__global__ __launch_bounds__(256)
void rtab_kernel(float2* __restrict__ tab)
{
  const int idx = blockIdx.x * 256 + threadIdx.x;
  const int s = idx >> 6, i = idx & 63;
  const float freq = __expf((float)i * -0.14391156831212787f);
  float sn, cs;
  sincosf((float)s * freq, &sn, &cs);
  const float sc = 0.29730177875068026f;
  tab[idx] = make_float2(cs * sc, sn * sc);
}

// im2col conv1: A1[(b*2048+t), i*3+kk] = x[b, i, 2t+kk-1] (pad 1), f32->bf16
__global__ __launch_bounds__(256)
void im2col1_kernel(const float* __restrict__ x, bf16_t* __restrict__ a)
{
  const long idx = (long)blockIdx.x * 256 + threadIdx.x;
  if (idx >= (long)NB * NT1 * 384) return;
  const int  k = (int)(idx % 384);
  const long m = idx / 384;
  const int i = k / 3, kk = k - 3 * i;
  const int t = (int)(m & (NT1 - 1));
  const int b = (int)(m >> 11);
  const int tt = 2 * t + kk - 1;
  float v = 0.0f;
  if (tt >= 0 && tt < NT) v = x[((long)b * 128 + i) * NT + tt];
  a[idx] = (bf16_t)v;
}

// im2col conv2: A2[(b*1024+t), i*3+kk] = h1[b, 2t+kk-1, i] (pad 1)
__global__ __launch_bounds__(256)
void im2col2_kernel(const bf16_t* __restrict__ h1, bf16_t* __restrict__ a)
{
  const long idx = (long)blockIdx.x * 256 + threadIdx.x;
  if (idx >= (long)NB * NS * 3072) return;
  const int  k = (int)(idx % 3072);
  const long m = idx / 3072;
  const int i = k / 3, kk = k - 3 * i;
  const int t = (int)(m & (NS - 1));
  const int b = (int)(m >> 10);
  const int tt = 2 * t + kk - 1;
  bf16_t v = (bf16_t)0.0f;
  if (tt >= 0 && tt < NT1) v = h1[((long)b * NT1 + tt) * ND + i];
  a[idx] = v;
}

__global__ void ylen_kernel(const int* __restrict__ xlen, float* __restrict__ ylen)
{
  const int b = threadIdx.x;
  if (b < NB) {
    const int y1 = (xlen[b] + 1) >> 1;
    ylen[b] = (float)((y1 + 1) >> 1);
  }
}

__global__ __launch_bounds__(256)
void cvt_kernel(const float* __restrict__ in, bf16_t* __restrict__ out, long n)
{
  const long i = ((long)blockIdx.x * 256 + threadIdx.x) * 4;
  if (i >= n) return;
  const float4 v = *reinterpret_cast<const float4*>(in + i);
  bf16x4 o;
  o[0] = (bf16_t)v.x; o[1] = (bf16_t)v.y; o[2] = (bf16_t)v.z; o[3] = (bf16_t)v.w;
  *reinterpret_cast<bf16x4*>(out + i) = o;
}

// per-layer weight conversion in ONE launch
__global__ __launch_bounds__(256)
void cvt_layer_kernel(const float* __restrict__ qw, const float* __restrict__ kw,
                      const float* __restrict__ vw, const float* __restrict__ ow,
                      const float* __restrict__ w1, const float* __restrict__ w2,
                      bf16_t* __restrict__ wqkv, bf16_t* __restrict__ wo,
                      bf16_t* __restrict__ w1b, bf16_t* __restrict__ w2b)
{
  const long i = ((long)blockIdx.x * 256 + threadIdx.x) * 4;
  const float* src; bf16_t* dst;
  if (i < 3145728) {
    dst = wqkv + i;
    if (i < 1048576)      { src = qw + i; }
    else if (i < 2097152) { src = kw + (i - 1048576); }
    else                  { src = vw + (i - 2097152); }
  } else if (i < 4194304) { src = ow + (i - 3145728); dst = wo  + (i - 3145728); }
  else if (i < 8388608)   { src = w1 + (i - 4194304); dst = w1b + (i - 4194304); }
  else                    { src = w2 + (i - 8388608); dst = w2b + (i - 8388608); }
  const float4 v = *reinterpret_cast<const float4*>(src);
  bf16x4 o;
  o[0] = (bf16_t)v.x; o[1] = (bf16_t)v.y; o[2] = (bf16_t)v.z; o[3] = (bf16_t)v.w;
  *reinterpret_cast<bf16x4*>(dst) = o;
}

extern "C" void kernel_launch(void* const* d_in, const int* in_sizes, int n_in,
                              void* d_out, int out_size, void* d_ws, size_t ws_size,
                              hipStream_t stream)
{
  const float* x         = (const float*)d_in[0];
  const int*   x_len     = (const int*)  d_in[1];
  const float* conv1_w   = (const float*)d_in[2];
  const float* conv1_b   = (const float*)d_in[3];
  const float* conv2_w   = (const float*)d_in[4];
  const float* conv2_b   = (const float*)d_in[5];
  const float* attn_ln_w = (const float*)d_in[6];
  const float* attn_ln_b = (const float*)d_in[7];
  const float* q_w   = (const float*)d_in[8];
  const float* q_b   = (const float*)d_in[9];
  const float* k_w   = (const float*)d_in[10];
  const float* v_w   = (const float*)d_in[11];
  const float* v_b   = (const float*)d_in[12];
  const float* out_w = (const float*)d_in[13];
  const float* out_b = (const float*)d_in[14];
  const float* mlp_ln_w = (const float*)d_in[15];
  const float* mlp_ln_b = (const float*)d_in[16];
  const float* mlp1_w = (const float*)d_in[17];
  const float* mlp1_b = (const float*)d_in[18];
  const float* mlp2_w = (const float*)d_in[19];
  const float* mlp2_b = (const float*)d_in[20];
  float* outp = (float*)d_out;
  (void)in_sizes; (void)n_in; (void)out_size;

  const long MB = 1024L * 1024;
  char* ws = (char*)d_ws;
  size_t off = 0;
  auto alloc = [&](size_t bytes) -> char* {
    char* p = ws + off;
    off += (bytes + 255) & ~(size_t)255;
    return p;
  };
  bf16_t* ybuf  = (bf16_t*)alloc(16 * MB);
  bf16_t* qbuf  = (bf16_t*)alloc(16 * MB);
  char*   R     = alloc(64 * MB);
  char*   wA    = alloc(25 * MB);
  const size_t required = off;

  bf16_t* a1  = ybuf;
  bf16_t* h1  = qbuf;
  bf16_t* a2  = (bf16_t*)(R + 16 * MB);
  bf16_t* c2w = (bf16_t*)wA;
  bf16_t* c1w = (bf16_t*)(wA + 8 * MB);
  float2* rtab = (float2*)(wA + 6 * MB);
  bf16_t* wqkv = (bf16_t*)wA;
  bf16_t* wo   = (bf16_t*)(wA + 6 * MB + 512 * 1024);
  bf16_t* w1b  = (bf16_t*)(wA + 9 * MB);
  bf16_t* w2b  = (bf16_t*)(wA + 17 * MB);
  bf16_t* kbuf = (bf16_t*)R;
  bf16_t* vt   = (bf16_t*)(R + 16 * MB);
  bf16_t* hid  = (bf16_t*)R;

  if (required > ws_size) {
    ylen_kernel<<<dim3(1), 64, 0, stream>>>(x_len, outp + 8L * 1024 * 1024);
    return;
  }

  auto cvt = [&](const float* in, bf16_t* o, long n) {
    cvt_kernel<<<dim3((unsigned)(n / 1024)), 256, 0, stream>>>(in, o, n);
  };

  rtab_kernel<<<dim3(256), 256, 0, stream>>>(rtab);

  // ---- conv stem ----
  cvt(conv1_w, c1w, 1024L * 384);
  cvt(conv2_w, c2w, 1024L * 3072);
  im2col1_kernel<<<dim3((unsigned)((16384L * 384) / 256)), 256, 0, stream>>>(x, a1);
  gemm_bt<EPI_GELU_BF16><<<dim3(128, 8), 512, 0, stream>>>(
      a1, 384, c1w, 384, h1, 1024, conv1_b, nullptr, 384, 1,
      nullptr, nullptr, nullptr, nullptr);
  im2col2_kernel<<<dim3((unsigned)((8192L * 3072) / 256)), 256, 0, stream>>>(h1, a2);
  gemm_bt<EPI_GELU_F32><<<dim3(64, 8), 512, 0, stream>>>(
      a2, 3072, c2w, 3072, outp /*carry*/, 1024, conv2_b, nullptr, 3072, 1,
      nullptr, nullptr, nullptr, nullptr);

  float* carry = outp;  // f32 residual stream lives in d_out

  for (int l = 0; l < 6; ++l) {
    cvt_layer_kernel<<<dim3(12288), 256, 0, stream>>>(
        q_w + (long)l * 1048576, k_w + (long)l * 1048576, v_w + (long)l * 1048576,
        out_w + (long)l * 1048576, mlp1_w + (long)l * 4194304, mlp2_w + (long)l * 4194304,
        wqkv, wo, w1b, w2b);

    ln_kernel<<<dim3(8192), 256, 0, stream>>>(carry, ybuf, attn_ln_w + l * 1024, attn_ln_b + l * 1024);

    // fused QKV projection + rope/scale + V-transpose (N=3072)
    gemm_bt<EPI_QKV><<<dim3(64, 24), 512, 0, stream>>>(
        ybuf, 1024, wqkv, 1024, qbuf, 1024,
        q_b + l * 1024, nullptr, 1024, 1, kbuf, vt, v_b + l * 1024, rtab);

    // flash attention: O overwrites Q in place
    flash_kernel<<<dim3(16, 64), 256, 0, stream>>>(qbuf, kbuf, vt, qbuf, x_len);

    // carry += O @ ow^T + ob
    gemm_bt<EPI_RES_F32><<<dim3(64, 8), 512, 0, stream>>>(
        qbuf, 1024, wo, 1024, carry, 1024,
        out_b + l * 1024, carry, 1024, 1, nullptr, nullptr, nullptr, nullptr);

    ln_kernel<<<dim3(8192), 256, 0, stream>>>(carry, ybuf, mlp_ln_w + l * 1024, mlp_ln_b + l * 1024);

    gemm_bt<EPI_GELU_BF16><<<dim3(64, 32), 512, 0, stream>>>(
        ybuf, 1024, w1b, 1024, hid, 4096,
        mlp1_b + (long)l * 4096, nullptr, 1024, 1, nullptr, nullptr, nullptr, nullptr);
    gemm_bt<EPI_RES_F32><<<dim3(64, 8), 512, 0, stream>>>(
        hid, 4096, w2b, 4096, carry, 1024,
        mlp2_b + l * 1024, carry, 4096, 1, nullptr, nullptr, nullptr, nullptr);
  }

  ylen_kernel<<<dim3(1), 64, 0, stream>>>(x_len, outp + 8L * 1024 * 1024);
}

// Round 20
// 2583.764 us; speedup vs baseline: 1.0990x; 1.0063x over previous
//
#include <hip/hip_runtime.h>
#include <hip/hip_bf16.h>
#include <cstdint>
#include <cstddef>

// ---------------------------------------------------------------------------
// AudioEncoder (Whisper-style) forward for MI355X.
// Base: r17/r19 config (2600 us). This round: MLP1 moves to gemm_w —
// 256x128 tile, 8 waves of 64x64 (acc[4][4]) -> 1.45x less LDS traffic per
// FLOP (the measured ~4000cy/K-step matches LDS-port time at ~85 B/cy;
// reuse, not occupancy/barriers, is the binding term). BK=32, NBUF=3,
// counted vmcnt(3) (r12's verified schedule). All else unchanged.
// ---------------------------------------------------------------------------

typedef __bf16 bf16_t;
typedef __bf16 bf16x8 __attribute__((ext_vector_type(8)));
typedef __bf16 bf16x4 __attribute__((ext_vector_type(4)));
typedef float  floatx4 __attribute__((ext_vector_type(4)));

#define NB   8
#define NS   1024
#define ND   1024
#define NT   4096
#define NT1  2048

#define MFMA16(a, b, c) __builtin_amdgcn_mfma_f32_16x16x32_bf16(a, b, c, 0, 0, 0)

#define SBAR() do { __builtin_amdgcn_sched_barrier(0); \
                    __builtin_amdgcn_s_barrier();      \
                    __builtin_amdgcn_sched_barrier(0); } while (0)

__device__ __forceinline__ float gelu_f(float x) {
  const float t = 1.5957691216057308f * (x + 0.044715f * x * x * x);
  return x / (1.0f + __expf(-t));
}

__device__ __forceinline__ void gload16(const void* g, void* l) {
  __builtin_amdgcn_global_load_lds(
      (__attribute__((address_space(1))) void*)(const_cast<void*>(g)),
      (__attribute__((address_space(3))) void*)l, 16, 0, 0);
}

enum { EPI_BF16 = 0, EPI_GELU_BF16 = 2, EPI_GELU_F32 = 3, EPI_RES_F32 = 4, EPI_QKV = 5 };

// 2-D per-XCD chunk remap (chunk = 16(bx) x cby(by), cby = gx*gy/128).
__device__ __forceinline__ void xcd_remap(int& bx, int& by) {
  const int gx = gridDim.x, gy = gridDim.y;
  const int id  = bx + by * gx;
  const int xcd = id & 7;
  const int r   = id >> 3;
  const int cby = (gx * gy) >> 7;
  const int ncx = gx >> 4;
  const int cx  = xcd % ncx, cy = xcd / ncx;
  bx = cx * 16 + (r & 15);
  by = cy * cby + (r >> 4);
}

// ==== r17 BK=64 kernel (unchanged) ====
#define COMPUTE2(BUF, H) { \
    const char* rAd = rA + (BUF) * 16384 + (H) * 8192; \
    const char* rBd = rB + (BUF) * 16384 + (H) * 8192; \
    const bf16x8 a0 = *(const bf16x8*)(rAd +    0); \
    const bf16x8 a1 = *(const bf16x8*)(rAd + 1024); \
    const bf16x8 a2 = *(const bf16x8*)(rAd + 2048); \
    const bf16x8 a3 = *(const bf16x8*)(rAd + 3072); \
    const bf16x8 b0 = *(const bf16x8*)(rBd +    0); \
    const bf16x8 b1 = *(const bf16x8*)(rBd + 1024); \
    acc[0][0] = MFMA16(a0, b0, acc[0][0]); acc[0][1] = MFMA16(a0, b1, acc[0][1]); \
    acc[1][0] = MFMA16(a1, b0, acc[1][0]); acc[1][1] = MFMA16(a1, b1, acc[1][1]); \
    acc[2][0] = MFMA16(a2, b0, acc[2][0]); acc[2][1] = MFMA16(a2, b1, acc[2][1]); \
    acc[3][0] = MFMA16(a3, b0, acc[3][0]); acc[3][1] = MFMA16(a3, b1, acc[3][1]); \
  }

#define KSTEP(BUF, SNEXT_OK) do { \
    if (SNEXT_OK) { \
      gload16(aP,      dA + ((BUF) ^ 1) * 8192);        \
      gload16(aP + 32, dA + ((BUF) ^ 1) * 8192 + 4096); \
    } \
    COMPUTE2(BUF, 0); \
    if (SNEXT_OK) { \
      gload16(bP,      dB + ((BUF) ^ 1) * 8192);        \
      gload16(bP + 32, dB + ((BUF) ^ 1) * 8192 + 4096); \
      aP += 64; bP += 64; \
    } \
    COMPUTE2(BUF, 1); \
    asm volatile("s_waitcnt vmcnt(0)" ::: "memory"); \
    SBAR(); \
  } while (0)

template<int EPI>
__global__ __launch_bounds__(512, 4)
void gemm_bt(const bf16_t* __restrict__ A, long lda,
             const bf16_t* __restrict__ Bm, long ldb,
             void* Cv, long ldc,
             const float* __restrict__ bias, const float* res,
             int K, int swz,
             bf16_t* out2, bf16_t* out3, const float* __restrict__ bias2,
             const float2* __restrict__ rtab)
{
  __shared__ bf16_t sA[2][8192];
  __shared__ bf16_t sB[2][8192];
  const int tid  = threadIdx.x;
  const int wid  = tid >> 6;
  const int lane = tid & 63;
  const int lo = lane & 15, g = lane >> 4;
  const int wr = wid >> 2, wc = wid & 3;

  int bx = blockIdx.x, by = blockIdx.y;
  if (swz) xcd_remap(bx, by);
  const int m0 = bx * 128, n0 = by * 128;
  const int NTK = K >> 6;

  const int lrow = lane >> 2;
  const int lcol = 8 * ((lane & 3) ^ ((lane >> 3) & 3));
  const int rslot = 16 * (g ^ ((lo >> 1) & 3));

  const bf16_t* aP = A  + (long)(m0 + wid * 16 + lrow) * lda + lcol;
  const bf16_t* bP = Bm + (long)(n0 + wid * 16 + lrow) * ldb + lcol;
  bf16_t* const dA = &sA[0][wid * 512];
  bf16_t* const dB = &sB[0][wid * 512];
  const char* const rA = (const char*)&sA[0][0] + (wr * 64 + lo) * 64 + rslot;
  const char* const rB = (const char*)&sB[0][0] + (wc * 32 + lo) * 64 + rslot;

  floatx4 acc[4][2] = {};

  gload16(aP,      dA);         gload16(aP + 32, dA + 4096);
  gload16(bP,      dB);         gload16(bP + 32, dB + 4096);
  aP += 64; bP += 64;
  asm volatile("s_waitcnt vmcnt(0)" ::: "memory");
  SBAR();

#pragma unroll 1
  for (int s = 0; s < NTK; s += 2) {
    KSTEP(0, (s + 1 < NTK));
    KSTEP(1, (s + 2 < NTK));
  }

  if constexpr (EPI == EPI_QKV) {
    const int sect = n0 >> 10;
#pragma unroll
    for (int ni = 0; ni < 2; ++ni) {
      const int col = n0 + wc * 32 + ni * 16 + lo;
      const int c10 = col & 1023;
      float bvs = 0.0f;
      if (sect == 0) bvs = bias[c10];
      else if (sect == 2) bvs = bias2[c10];
#pragma unroll
      for (int mi = 0; mi < 4; ++mi) {
#pragma unroll
        for (int r = 0; r < 4; ++r) {
          const int row = m0 + wr * 64 + mi * 16 + g * 4 + r;
          const int sr = row & 1023;
          float val = acc[mi][ni][r] + bvs;
          if (sect < 2) {
            const float2 t = rtab[(sr << 6) + ((col & 127) >> 1)];
            const float p = __shfl_xor(val, 1);
            val = val * t.x + p * ((col & 1) ? t.y : -t.y);
            bf16_t* dst = sect ? out2 : (bf16_t*)Cv;
            dst[(long)row * 1024 + c10] = (bf16_t)val;
          } else {
            out3[((long)(row >> 10) << 20) + ((long)(col - 2048) << 10) + sr] = (bf16_t)val;
          }
        }
      }
    }
    return;
  }

#pragma unroll
  for (int ni = 0; ni < 2; ++ni) {
    const int col = n0 + wc * 32 + ni * 16 + lo;
    const float bvs = bias ? bias[col] : 0.0f;
#pragma unroll
    for (int mi = 0; mi < 4; ++mi) {
#pragma unroll
      for (int r = 0; r < 4; ++r) {
        const int row = m0 + wr * 64 + mi * 16 + g * 4 + r;
        float v = acc[mi][ni][r] + bvs;
        if constexpr (EPI == EPI_BF16) {
          ((bf16_t*)Cv)[(long)row * ldc + col] = (bf16_t)v;
        } else if constexpr (EPI == EPI_GELU_BF16) {
          ((bf16_t*)Cv)[(long)row * ldc + col] = (bf16_t)gelu_f(v);
        } else if constexpr (EPI == EPI_GELU_F32) {
          ((float*)Cv)[(long)row * ldc + col] = gelu_f(v);
        } else {  // EPI_RES_F32
          const long idx = (long)row * ldc + col;
          ((float*)Cv)[idx] = res[idx] + v;
        }
      }
    }
  }
}

// ---------------------------------------------------------------------------
// gemm_w: wide-reuse GEMM for MLP1. 256x128 tile, 8 waves (4Mx2N), each wave
// 64x64 output acc[4][4]. BK=32, NBUF=3 (A 16KB + B 8KB per buf = 72KB LDS,
// 2 blocks/CU), counted vmcnt(3): per wave 3 gloads/step (2 A-segs + 1 B-seg,
// 16-row x 1KB segments, same proven write/read swizzle involution).
// Epilogue: gelu -> bf16.
// ---------------------------------------------------------------------------
__global__ __launch_bounds__(512, 4)
void gemm_w(const bf16_t* __restrict__ A, long lda,
            const bf16_t* __restrict__ Bm, long ldb,
            bf16_t* __restrict__ C, long ldc,
            const float* __restrict__ bias, int K)
{
  __shared__ bf16_t sA[3][8192];   // [buf][256 rows x 32]  16KB/buf
  __shared__ bf16_t sB[3][4096];   // [buf][128 rows x 32]   8KB/buf
  const int tid  = threadIdx.x;
  const int wid  = tid >> 6;
  const int lane = tid & 63;
  const int lo = lane & 15, g = lane >> 4;
  const int wr = wid >> 1, wc = wid & 1;   // 4M x 2N wave grid

  int bx = blockIdx.x, by = blockIdx.y;
  xcd_remap(bx, by);                 // (32,32): ncx=2, cby=8 -> bijective
  const int m0 = bx * 256, n0 = by * 128;
  const int NTK = K >> 5;

  const int lrow = lane >> 2;
  const int lcol = 8 * ((lane & 3) ^ ((lane >> 3) & 3));   // inv-swizzled src
  const int rslot = 16 * (g ^ ((lo >> 1) & 3));            // read-side XOR

  // per-lane global sources (advance +32/tile), wave-uniform LDS dests
  const bf16_t* a0P = A  + (long)(m0 + (wid * 2)     * 16 + lrow) * lda + lcol;
  const bf16_t* a1P = A  + (long)(m0 + (wid * 2 + 1) * 16 + lrow) * lda + lcol;
  const bf16_t* bP  = Bm + (long)(n0 + wid * 16 + lrow) * ldb + lcol;
  bf16_t* const dA0 = &sA[0][(wid * 2)     * 512];
  bf16_t* const dA1 = &sA[0][(wid * 2 + 1) * 512];
  bf16_t* const dB  = &sB[0][wid * 512];
  const char* const rA = (const char*)&sA[0][0] + (wr * 64 + lo) * 64 + rslot;
  const char* const rB = (const char*)&sB[0][0] + (wc * 64 + lo) * 64 + rslot;

  floatx4 acc[4][4] = {};

  auto stage = [&](int t) {
    const int buf = t % 3;
    gload16(a0P, dA0 + buf * 8192);
    gload16(a1P, dA1 + buf * 8192);
    gload16(bP,  dB  + buf * 4096);
    a0P += 32; a1P += 32; bP += 32;
  };

  // prologue: stage tiles 0,1 (NTK = 32 for K=1024)
  stage(0); stage(1);
  asm volatile("s_waitcnt vmcnt(3)" ::: "memory");   // tile0 landed
  SBAR();

#pragma unroll 1
  for (int s = 0; s < NTK; ++s) {
    if (s + 2 < NTK) stage(s + 2);
    const int buf = s % 3;
    const char* rAd = rA + buf * 16384;
    const char* rBd = rB + buf * 8192;
    bf16x8 av[4], bv[4];
#pragma unroll
    for (int i = 0; i < 4; ++i) av[i] = *(const bf16x8*)(rAd + i * 1024);
#pragma unroll
    for (int i = 0; i < 4; ++i) bv[i] = *(const bf16x8*)(rBd + i * 1024);
#pragma unroll
    for (int mi = 0; mi < 4; ++mi)
#pragma unroll
      for (int ni = 0; ni < 4; ++ni)
        acc[mi][ni] = MFMA16(av[mi], bv[ni], acc[mi][ni]);
    if (s + 2 < NTK) { asm volatile("s_waitcnt vmcnt(3)" ::: "memory"); }
    else             { asm volatile("s_waitcnt vmcnt(0)" ::: "memory"); }
    SBAR();
  }

  // epilogue: wave rows m0+wr*64+[0,64), cols n0+wc*64+[0,64); gelu -> bf16
#pragma unroll
  for (int ni = 0; ni < 4; ++ni) {
    const int col = n0 + wc * 64 + ni * 16 + lo;
    const float bvs = bias[col];
#pragma unroll
    for (int mi = 0; mi < 4; ++mi) {
#pragma unroll
      for (int r = 0; r < 4; ++r) {
        const int row = m0 + wr * 64 + mi * 16 + g * 4 + r;
        C[(long)row * ldc + col] = (bf16_t)gelu_f(acc[mi][ni][r] + bvs);
      }
    }
  }
}

// ---------------------------------------------------------------------------
// Flash attention (unchanged from round 11).
// ---------------------------------------------------------------------------
__global__ __launch_bounds__(256, 4)
void flash_kernel(const bf16_t* __restrict__ q, const bf16_t* __restrict__ k,
                  const bf16_t* __restrict__ vt, bf16_t* __restrict__ o,
                  const int* __restrict__ xlen)
{
  __shared__ bf16_t sK[2][4096];
  __shared__ bf16_t sV[2][4096];
  __shared__ bf16_t sP[4][512];
  const int tid = threadIdx.x, w = tid >> 6, lane = tid & 63;
  const int lo = lane & 15, g = lane >> 4;
  const int hid = blockIdx.x + (blockIdx.y << 4);
  const int h   = hid & 7;
  const int qx  = (hid >> 3) & 15;
  const int b   = hid >> 7;
  const int q0 = qx * 64 + w * 16;
  const int nv  = xlen[b] >> 2;
  const int nkt = (nv + 31) >> 5;
  const long base = (long)b * 1048576 + (long)h * 128;
  const bf16_t* Qp = q + base;
  const bf16_t* Kp = k + base;
  const bf16_t* Vp = vt + (long)b * 1048576 + ((long)h << 17);

  auto stageKV = [&](int kt, int buf) {
    const int kv0 = kt << 5;
#pragma unroll
    for (int jj = 0; jj < 2; ++jj) {
      const int seg = (w << 1) + jj;
      {
        const int row = (seg << 2) + (lane >> 4);
        const int col = ((lane & 15) << 3) ^ ((row & 7) << 3);
        gload16(Kp + (long)(kv0 + row) * 1024 + col, &sK[buf][seg * 512]);
      }
      {
        const int row = (seg << 4) + (lane >> 2);
        const int col = ((lane & 3) << 3) ^ ((row & 3) << 3);
        gload16(Vp + (long)row * 1024 + kv0 + col, &sV[buf][seg * 512]);
      }
    }
  };

  bf16x8 qf[4];
#pragma unroll
  for (int ks = 0; ks < 4; ++ks)
    qf[ks] = *reinterpret_cast<const bf16x8*>(
        Qp + (long)(q0 + lo) * 1024 + ks * 32 + g * 8);

  floatx4 of[8] = {};
  float m[4], l[4];
#pragma unroll
  for (int r = 0; r < 4; ++r) { m[r] = -1e30f; l[r] = 0.0f; }

  const char* kbase = (const char*)&sK[0][0];
  const char* vbase = (const char*)&sV[0][0];
  char* pbase = (char*)&sP[w][0];
  const int swzK = (lo & 7) << 4;
  const int swzV = (lo & 3) << 4;

  stageKV(0, 0);
  __syncthreads();
  int cur = 0;
#pragma unroll 1
  for (int kt = 0; kt < nkt; ++kt) {
    const int kv0 = kt << 5;
    if (kt + 1 < nkt) stageKV(kt + 1, cur ^ 1);

    floatx4 s[2] = {};
    __builtin_amdgcn_s_setprio(1);
#pragma unroll
    for (int ni = 0; ni < 2; ++ni) {
#pragma unroll
      for (int ks = 0; ks < 4; ++ks) {
        const bf16x8 bv = *reinterpret_cast<const bf16x8*>(
            kbase + cur * 8192 + (ni * 16 + lo) * 256 + ((ks * 64 + (g << 4)) ^ swzK));
        s[ni] = MFMA16(qf[ks], bv, s[ni]);
      }
    }
    __builtin_amdgcn_s_setprio(0);

    float pmv[4];
#pragma unroll
    for (int r = 0; r < 4; ++r) {
      float pm = -1e30f;
#pragma unroll
      for (int ni = 0; ni < 2; ++ni) {
        float val = s[ni][r];
        if (kv0 + ni * 16 + lo >= nv) val = -1e30f;
        pm = fmaxf(pm, val);
      }
      pm = fmaxf(pm, __shfl_xor(pm, 1)); pm = fmaxf(pm, __shfl_xor(pm, 2));
      pm = fmaxf(pm, __shfl_xor(pm, 4)); pm = fmaxf(pm, __shfl_xor(pm, 8));
      pmv[r] = pm;
    }
    const bool skip = __all((pmv[0] <= m[0] + 8.0f) & (pmv[1] <= m[1] + 8.0f) &
                            (pmv[2] <= m[2] + 8.0f) & (pmv[3] <= m[3] + 8.0f));

#pragma unroll
    for (int r = 0; r < 4; ++r) {
      float mn = m[r];
      if (!skip) {
        mn = fmaxf(m[r], pmv[r]);
        const float sc = __expf(m[r] - mn);
        l[r] *= sc;
#pragma unroll
        for (int nd = 0; nd < 8; ++nd) of[nd][r] *= sc;
        m[r] = mn;
      }
      const int qrow = g * 4 + r;
      const int sw = (qrow & 3) << 4;
      float ss = 0.0f;
#pragma unroll
      for (int ni = 0; ni < 2; ++ni) {
        float val = s[ni][r];
        if (kv0 + ni * 16 + lo >= nv) val = -1e30f;
        const float p = __expf(val - mn);
        ss += p;
        *(bf16_t*)(pbase + qrow * 64 + (((ni << 5) + (lo << 1)) ^ sw)) = (bf16_t)p;
      }
      ss += __shfl_xor(ss, 1); ss += __shfl_xor(ss, 2);
      ss += __shfl_xor(ss, 4); ss += __shfl_xor(ss, 8);
      l[r] += ss;
    }

    asm volatile("s_waitcnt lgkmcnt(0)" ::: "memory");
    __builtin_amdgcn_sched_barrier(0);

    __builtin_amdgcn_s_setprio(1);
    {
      const bf16x8 av = *reinterpret_cast<const bf16x8*>(
          pbase + lo * 64 + ((g << 4) ^ swzV));
#pragma unroll
      for (int nd = 0; nd < 8; ++nd) {
        const bf16x8 bv = *reinterpret_cast<const bf16x8*>(
            vbase + cur * 8192 + (nd * 16 + lo) * 64 + ((g << 4) ^ swzV));
        of[nd] = MFMA16(av, bv, of[nd]);
      }
    }
    __builtin_amdgcn_s_setprio(0);
    __syncthreads();
    cur ^= 1;
  }

#pragma unroll
  for (int r = 0; r < 4; ++r) {
    const float inv = 1.0f / l[r];
    const long rb = base + (long)(q0 + g * 4 + r) * 1024;
#pragma unroll
    for (int nd = 0; nd < 8; ++nd)
      o[rb + nd * 16 + lo] = (bf16_t)(of[nd][r] * inv);
  }
}

// LayerNorm: one block per row of 1024 f32 -> bf16
__global__ __launch_bounds__(256)
void ln_kernel(const float* __restrict__ x, bf16_t* __restrict__ y,
               const float* __restrict__ w, const float* __restrict__ b)
{
  const long row = blockIdx.x;
  const float4 v = reinterpret_cast<const float4*>(x + row * ND)[threadIdx.x];
  float s  = v.x + v.y + v.z + v.w;
  float ss = v.x * v.x + v.y * v.y + v.z * v.z + v.w * v.w;
#pragma unroll
  for (int off = 32; off; off >>= 1) { s += __shfl_down(s, off); ss += __shfl_down(ss, off); }
  __shared__ float sh[8];
  if ((threadIdx.x & 63) == 0) { sh[threadIdx.x >> 6] = s; sh[4 + (threadIdx.x >> 6)] = ss; }
  __syncthreads();
  const float tot  = sh[0] + sh[1] + sh[2] + sh[3];
  const float tot2 = sh[4] + sh[5] + sh[6] + sh[7];
  const float mean = tot * (1.0f / ND);
  const float var  = tot2 * (1.0f / ND) - mean * mean;
  const float rstd = rsqrtf(var + 1e-5f);
  const int i0 = threadIdx.x * 4;
  const float vv[4] = {v.x, v.y, v.z, v.w};
  bf16x4 o;
#pragma unroll
  for (int j = 0; j < 4; ++j)
    o[j] = (bf16_t)((vv[j] - mean) * rstd * w[i0 + j] + b[i0 + j]);
  reinterpret_cast<bf16x4*>(y + row * ND)[threadIdx.x] = o;
}

// pre-scaled rope table: rtab[s*64+i] = (cos, sin)(s*f_i) * 128^-0.25
__global__ __launch_bounds__(256)
void rtab_kernel(float2* __restrict__ tab)
{
  const int idx = blockIdx.x * 256 + threadIdx.x;
  const int s = idx >> 6, i = idx & 63;
  const float freq = __expf((float)i * -0.14391156831212787f);
  float sn, cs;
  sincosf((float)s * freq, &sn, &cs);
  const float sc = 0.29730177875068026f;
  tab[idx] = make_float2(cs * sc, sn * sc);
}

// im2col conv1: A1[(b*2048+t), i*3+kk] = x[b, i, 2t+kk-1] (pad 1), f32->bf16
__global__ __launch_bounds__(256)
void im2col1_kernel(const float* __restrict__ x, bf16_t* __restrict__ a)
{
  const long idx = (long)blockIdx.x * 256 + threadIdx.x;
  if (idx >= (long)NB * NT1 * 384) return;
  const int  k = (int)(idx % 384);
  const long m = idx / 384;
  const int i = k / 3, kk = k - 3 * i;
  const int t = (int)(m & (NT1 - 1));
  const int b = (int)(m >> 11);
  const int tt = 2 * t + kk - 1;
  float v = 0.0f;
  if (tt >= 0 && tt < NT) v = x[((long)b * 128 + i) * NT + tt];
  a[idx] = (bf16_t)v;
}

// im2col conv2: A2[(b*1024+t), i*3+kk] = h1[b, 2t+kk-1, i] (pad 1)
__global__ __launch_bounds__(256)
void im2col2_kernel(const bf16_t* __restrict__ h1, bf16_t* __restrict__ a)
{
  const long idx = (long)blockIdx.x * 256 + threadIdx.x;
  if (idx >= (long)NB * NS * 3072) return;
  const int  k = (int)(idx % 3072);
  const long m = idx / 3072;
  const int i = k / 3, kk = k - 3 * i;
  const int t = (int)(m & (NS - 1));
  const int b = (int)(m >> 10);
  const int tt = 2 * t + kk - 1;
  bf16_t v = (bf16_t)0.0f;
  if (tt >= 0 && tt < NT1) v = h1[((long)b * NT1 + tt) * ND + i];
  a[idx] = v;
}

__global__ void ylen_kernel(const int* __restrict__ xlen, float* __restrict__ ylen)
{
  const int b = threadIdx.x;
  if (b < NB) {
    const int y1 = (xlen[b] + 1) >> 1;
    ylen[b] = (float)((y1 + 1) >> 1);
  }
}

__global__ __launch_bounds__(256)
void cvt_kernel(const float* __restrict__ in, bf16_t* __restrict__ out, long n)
{
  const long i = ((long)blockIdx.x * 256 + threadIdx.x) * 4;
  if (i >= n) return;
  const float4 v = *reinterpret_cast<const float4*>(in + i);
  bf16x4 o;
  o[0] = (bf16_t)v.x; o[1] = (bf16_t)v.y; o[2] = (bf16_t)v.z; o[3] = (bf16_t)v.w;
  *reinterpret_cast<bf16x4*>(out + i) = o;
}

// per-layer weight conversion in ONE launch
__global__ __launch_bounds__(256)
void cvt_layer_kernel(const float* __restrict__ qw, const float* __restrict__ kw,
                      const float* __restrict__ vw, const float* __restrict__ ow,
                      const float* __restrict__ w1, const float* __restrict__ w2,
                      bf16_t* __restrict__ wqkv, bf16_t* __restrict__ wo,
                      bf16_t* __restrict__ w1b, bf16_t* __restrict__ w2b)
{
  const long i = ((long)blockIdx.x * 256 + threadIdx.x) * 4;
  const float* src; bf16_t* dst;
  if (i < 3145728) {
    dst = wqkv + i;
    if (i < 1048576)      { src = qw + i; }
    else if (i < 2097152) { src = kw + (i - 1048576); }
    else                  { src = vw + (i - 2097152); }
  } else if (i < 4194304) { src = ow + (i - 3145728); dst = wo  + (i - 3145728); }
  else if (i < 8388608)   { src = w1 + (i - 4194304); dst = w1b + (i - 4194304); }
  else                    { src = w2 + (i - 8388608); dst = w2b + (i - 8388608); }
  const float4 v = *reinterpret_cast<const float4*>(src);
  bf16x4 o;
  o[0] = (bf16_t)v.x; o[1] = (bf16_t)v.y; o[2] = (bf16_t)v.z; o[3] = (bf16_t)v.w;
  *reinterpret_cast<bf16x4*>(dst) = o;
}

extern "C" void kernel_launch(void* const* d_in, const int* in_sizes, int n_in,
                              void* d_out, int out_size, void* d_ws, size_t ws_size,
                              hipStream_t stream)
{
  const float* x         = (const float*)d_in[0];
  const int*   x_len     = (const int*)  d_in[1];
  const float* conv1_w   = (const float*)d_in[2];
  const float* conv1_b   = (const float*)d_in[3];
  const float* conv2_w   = (const float*)d_in[4];
  const float* conv2_b   = (const float*)d_in[5];
  const float* attn_ln_w = (const float*)d_in[6];
  const float* attn_ln_b = (const float*)d_in[7];
  const float* q_w   = (const float*)d_in[8];
  const float* q_b   = (const float*)d_in[9];
  const float* k_w   = (const float*)d_in[10];
  const float* v_w   = (const float*)d_in[11];
  const float* v_b   = (const float*)d_in[12];
  const float* out_w = (const float*)d_in[13];
  const float* out_b = (const float*)d_in[14];
  const float* mlp_ln_w = (const float*)d_in[15];
  const float* mlp_ln_b = (const float*)d_in[16];
  const float* mlp1_w = (const float*)d_in[17];
  const float* mlp1_b = (const float*)d_in[18];
  const float* mlp2_w = (const float*)d_in[19];
  const float* mlp2_b = (const float*)d_in[20];
  float* outp = (float*)d_out;
  (void)in_sizes; (void)n_in; (void)out_size;

  const long MB = 1024L * 1024;
  char* ws = (char*)d_ws;
  size_t off = 0;
  auto alloc = [&](size_t bytes) -> char* {
    char* p = ws + off;
    off += (bytes + 255) & ~(size_t)255;
    return p;
  };
  bf16_t* ybuf  = (bf16_t*)alloc(16 * MB);
  bf16_t* qbuf  = (bf16_t*)alloc(16 * MB);
  char*   R     = alloc(64 * MB);
  char*   wA    = alloc(25 * MB);
  const size_t required = off;

  bf16_t* a1  = ybuf;
  bf16_t* h1  = qbuf;
  bf16_t* a2  = (bf16_t*)(R + 16 * MB);
  bf16_t* c2w = (bf16_t*)wA;
  bf16_t* c1w = (bf16_t*)(wA + 8 * MB);
  float2* rtab = (float2*)(wA + 6 * MB);
  bf16_t* wqkv = (bf16_t*)wA;
  bf16_t* wo   = (bf16_t*)(wA + 6 * MB + 512 * 1024);
  bf16_t* w1b  = (bf16_t*)(wA + 9 * MB);
  bf16_t* w2b  = (bf16_t*)(wA + 17 * MB);
  bf16_t* kbuf = (bf16_t*)R;
  bf16_t* vt   = (bf16_t*)(R + 16 * MB);
  bf16_t* hid  = (bf16_t*)R;

  if (required > ws_size) {
    ylen_kernel<<<dim3(1), 64, 0, stream>>>(x_len, outp + 8L * 1024 * 1024);
    return;
  }

  auto cvt = [&](const float* in, bf16_t* o, long n) {
    cvt_kernel<<<dim3((unsigned)(n / 1024)), 256, 0, stream>>>(in, o, n);
  };

  rtab_kernel<<<dim3(256), 256, 0, stream>>>(rtab);

  // ---- conv stem ----
  cvt(conv1_w, c1w, 1024L * 384);
  cvt(conv2_w, c2w, 1024L * 3072);
  im2col1_kernel<<<dim3((unsigned)((16384L * 384) / 256)), 256, 0, stream>>>(x, a1);
  gemm_bt<EPI_GELU_BF16><<<dim3(128, 8), 512, 0, stream>>>(
      a1, 384, c1w, 384, h1, 1024, conv1_b, nullptr, 384, 1,
      nullptr, nullptr, nullptr, nullptr);
  im2col2_kernel<<<dim3((unsigned)((8192L * 3072) / 256)), 256, 0, stream>>>(h1, a2);
  gemm_bt<EPI_GELU_F32><<<dim3(64, 8), 512, 0, stream>>>(
      a2, 3072, c2w, 3072, outp /*carry*/, 1024, conv2_b, nullptr, 3072, 1,
      nullptr, nullptr, nullptr, nullptr);

  float* carry = outp;  // f32 residual stream lives in d_out

  for (int l = 0; l < 6; ++l) {
    cvt_layer_kernel<<<dim3(12288), 256, 0, stream>>>(
        q_w + (long)l * 1048576, k_w + (long)l * 1048576, v_w + (long)l * 1048576,
        out_w + (long)l * 1048576, mlp1_w + (long)l * 4194304, mlp2_w + (long)l * 4194304,
        wqkv, wo, w1b, w2b);

    ln_kernel<<<dim3(8192), 256, 0, stream>>>(carry, ybuf, attn_ln_w + l * 1024, attn_ln_b + l * 1024);

    // fused QKV projection + rope/scale + V-transpose (N=3072)
    gemm_bt<EPI_QKV><<<dim3(64, 24), 512, 0, stream>>>(
        ybuf, 1024, wqkv, 1024, qbuf, 1024,
        q_b + l * 1024, nullptr, 1024, 1, kbuf, vt, v_b + l * 1024, rtab);

    // flash attention: O overwrites Q in place
    flash_kernel<<<dim3(16, 64), 256, 0, stream>>>(qbuf, kbuf, vt, qbuf, x_len);

    // carry += O @ ow^T + ob
    gemm_bt<EPI_RES_F32><<<dim3(64, 8), 512, 0, stream>>>(
        qbuf, 1024, wo, 1024, carry, 1024,
        out_b + l * 1024, carry, 1024, 1, nullptr, nullptr, nullptr, nullptr);

    ln_kernel<<<dim3(8192), 256, 0, stream>>>(carry, ybuf, mlp_ln_w + l * 1024, mlp_ln_b + l * 1024);

    // hid = gelu(y @ w1^T + b1) -- wide-reuse 256x128 kernel
    gemm_w<<<dim3(32, 32), 512, 0, stream>>>(
        ybuf, 1024, w1b, 1024, hid, 4096, mlp1_b + (long)l * 4096, 1024);

    gemm_bt<EPI_RES_F32><<<dim3(64, 8), 512, 0, stream>>>(
        hid, 4096, w2b, 4096, carry, 1024,
        mlp2_b + l * 1024, carry, 4096, 1, nullptr, nullptr, nullptr, nullptr);
  }

  ylen_kernel<<<dim3(1), 64, 0, stream>>>(x_len, outp + 8L * 1024 * 1024);
}